// Round 5
// baseline (190.245 us; speedup 1.0000x reference)
//
#include <hip/hip_runtime.h>
#include <hip/hip_fp16.h>

// Capsule dynamic routing: tiny prep + ONE fused kernel (plain launch).
// x:[B,I,K]=32x2048x8, W:[J,I,D,K]=32x2048x16x8, out v:[B,J,D]=32x32x16.
// R10: R9 kernel = 113us but VALUBusy 17.5% -> ~20us work, ~90us wait.
// Two suspects attacked: (1) barrier flag contention: 255 pollers hammered
// ONE cache line (~700 agent loads/us -> L2 bank saturation delays the
// release store). Now 32 flag lines (block polls line bid&31, ~8/line,
// sleep(16) backoff). (2) in-kernel W stage was fp32 fetch + VALU convert
// + latency-serialized (33.5MB fp32). Now a prep kernel converts W->f16
// PRE-SWIZZLED into ws at streaming BW; fused stage is a pure contiguous
// 64KB/block f16 copy (int4 load + ds_write_b128, no converts, half bytes).
// Barrier arrival slots stay distributed (own 128B line per block);
// 87040B LDS pad still forces 1 block/CU so plain launch == coop placement.
// Routing math is bit-identical to R6-R9 (absmax must stay 0.00390625).

#define ICAP    2048
#define JD      512          // JCAP*DDIM
#define S_ELEMS 16384        // BATCH*JCAP*DDIM
#define EPSQ    1e-7f
#define NBP     256          // blocks (one 8-i chunk each)
#define ICH     8            // i's per block
#define WROW    1040         // 64 slots x 16B + 16B pad
#define WIL     (8 * WROW)   // per-il LDS bytes (8 rr rows)

// gbar layout (unsigned words):
//   words [f*32], f=0..31   : 32 release-flag lines (one 128B line each)
//   words [1024 + b*32]     : block b's arrival slot (one 128B line each)
#define GBAR_WORDS (1024 + NBP * 32)

typedef _Float16 h2v __attribute__((ext_vector_type(2)));
union H8 { int4 i4; h2v h[4]; };

#if defined(__has_builtin) && __has_builtin(__builtin_amdgcn_fdot2)
#define FDOT2(a, b, c) __builtin_amdgcn_fdot2((a), (b), (c), false)
#else
__device__ inline float FDOT2(h2v a, h2v b, float c) {
    return c + (float)a[0] * (float)b[0] + (float)a[1] * (float)b[1];
}
#endif
#if defined(__has_builtin) && __has_builtin(__builtin_amdgcn_rcpf)
#define FAST_RCP(x) __builtin_amdgcn_rcpf(x)
#else
#define FAST_RCP(x) (1.0f / (x))
#endif
#if defined(__has_builtin) && __has_builtin(__builtin_amdgcn_rsqf)
#define FAST_RSQ(x) __builtin_amdgcn_rsqf(x)
#else
#define FAST_RSQ(x) rsqrtf(x)
#endif

// ---------------------------------------------------------------------------
// Prep: W fp32 -> f16, PRE-SWIZZLED to the fused kernel's LDS layout.
// Wt byte offset = bid*65536 + (il*8 + rr)*1024 + slot*16, where
// bid=i>>3, il=i&7, rr=d&7, slot=2*j+(d>>3); the 16B slot holds halves of
// W[j][i][d][k=0..7]. Thread (i, slot) loops rr: reads 256B contiguous
// fp32, writes 8 x 16B (coalesced 1KB per wave per rr). 512 blocks x 256.
// ---------------------------------------------------------------------------
__global__ __launch_bounds__(256)
void caps_prep(const float4* __restrict__ Wv, char* __restrict__ Wt) {
    const int t = threadIdx.x;
    const int i = blockIdx.x * 4 + (t >> 6);
    const int slot = t & 63;
    const int j = slot >> 1, dh = slot & 1;
    const float4* src = Wv + (((size_t)j * ICAP + i) * 16 + dh * 8) * 2;
    char* dst = Wt + ((size_t)(i >> 3) * 64 + (i & 7) * 8) * 1024 + slot * 16;
#pragma unroll
    for (int rr = 0; rr < 8; ++rr) {
        const float4 a = src[rr * 2];
        const float4 b = src[rr * 2 + 1];
        union { int4 v; ushort u[8]; } pk;
        pk.u[0] = __half_as_ushort(__float2half(a.x));
        pk.u[1] = __half_as_ushort(__float2half(a.y));
        pk.u[2] = __half_as_ushort(__float2half(a.z));
        pk.u[3] = __half_as_ushort(__float2half(a.w));
        pk.u[4] = __half_as_ushort(__float2half(b.x));
        pk.u[5] = __half_as_ushort(__float2half(b.y));
        pk.u[6] = __half_as_ushort(__float2half(b.z));
        pk.u[7] = __half_as_ushort(__float2half(b.w));
        *reinterpret_cast<int4*>(dst + rr * 1024) = pk.v;
    }
}

// ---------------------------------------------------------------------------
// Distributed-arrival grid barrier with 32-way flag broadcast.
// Requires co-resident grid (LDS capacity forces 1 block/CU, grid==#CUs)
// and zeroed state. Visibility: writer __threadfence + relaxed agent slot
// store; checker relaxed-polls 256 slots, fences, stores 32 flag copies;
// pollers relaxed-spin on their flag line then fence. (Scheme passed R7-R9.)
// ---------------------------------------------------------------------------
__device__ __forceinline__ void gsync(unsigned* gb, unsigned gen,
                                      int bid, int tid) {
    __syncthreads();
    if (tid == 0) {
        __threadfence();     // release: prior global stores before arrival
        __hip_atomic_store(gb + 1024 + bid * 32, gen, __ATOMIC_RELAXED,
                           __HIP_MEMORY_SCOPE_AGENT);
    }
    if (bid == 0) {
        if (tid < 64) {
            const unsigned* s = gb + 1024 + tid * 32;
            for (;;) {
                bool done = true;
#pragma unroll
                for (int q = 0; q < 4; ++q) {
                    const unsigned v = __hip_atomic_load(
                        s + q * 2048, __ATOMIC_RELAXED,
                        __HIP_MEMORY_SCOPE_AGENT);
                    done &= (v >= gen);
                }
                if (__all(done)) break;
                __builtin_amdgcn_s_sleep(1);
            }
            __threadfence(); // acquire (transitive to flag stores)
            if (tid < 32)
                __hip_atomic_store(gb + tid * 32, gen, __ATOMIC_RELAXED,
                                   __HIP_MEMORY_SCOPE_AGENT);
        }
    } else if (tid == 0) {
        const unsigned* flag = gb + (bid & 31) * 32;
        while (__hip_atomic_load(flag, __ATOMIC_RELAXED,
                                 __HIP_MEMORY_SCOPE_AGENT) < gen)
            __builtin_amdgcn_s_sleep(16);
        __threadfence();     // acquire
    }
    __syncthreads();
}

// ---------------------------------------------------------------------------
// Fused kernel: 256 blocks x 512 threads (8 waves), 1 block/CU (LDS-forced).
// Wave w owns b in {w, w+8, w+16, w+24}; lane l -> j = l&31, dh = l>>5.
// LDS: sWt 66.5KB (pre-swizzled f16 W chunk), sX 4KB, rbuf 16KB pad.
// ---------------------------------------------------------------------------
__global__ __launch_bounds__(512, 1)
void caps_fused(const int4* __restrict__ Wtp, const float4* __restrict__ Xv,
                float* __restrict__ vsum, __half* __restrict__ partials,
                float* __restrict__ out, unsigned* __restrict__ gbar)
{
    __shared__ __align__(16) unsigned char sWt[WIL * ICH];   // 66560 B
    __shared__ __align__(16) unsigned char sX[4096];         // 32b x 8il x 16B
    __shared__ float rbuf[8][512];                           // 16KB (occupancy pad)

    const int tid  = threadIdx.x;
    const int bid  = blockIdx.x;
    const int i0   = bid * ICH;
    const int wave = tid >> 6, lane = tid & 63;

    // ---- stage W: pre-swizzled f16 global -> LDS, pure 64KB copy ----
    // row rid = il*8+rr is 1024B contiguous both in global and (padded) LDS.
    {
        const int4* wsrc = Wtp + ((size_t)bid * 65536 >> 4);
#pragma unroll
        for (int n = 0; n < 8; ++n) {
            const int rid = wave * 8 + n;
            const int il = rid >> 3, rr = rid & 7;
            const int4 v = wsrc[(size_t)rid * 64 + lane];
            *reinterpret_cast<int4*>(sWt + il * WIL + rr * WROW + lane * 16) = v;
        }
    }
    // ---- stage x: fp32 global -> f16 LDS, slot (b*8+il)*16B = x[b,i,0..7] ----
    {
        const int k4 = tid & 1, il = (tid >> 1) & 7, b = tid >> 4;
        const float4 w = Xv[((size_t)b * ICAP + (i0 + il)) * 2 + k4];
        ushort4 h;
        h.x = __half_as_ushort(__float2half(w.x));
        h.y = __half_as_ushort(__float2half(w.y));
        h.z = __half_as_ushort(__float2half(w.z));
        h.w = __half_as_ushort(__float2half(w.w));
        *reinterpret_cast<ushort4*>(sX + (b * 8 + il) * 16 + k4 * 8) = h;
    }
    __syncthreads();

    const int j = lane & 31, dh = lane >> 5;
    float vacc = 0.f;                            // wave-0: running vsum[e]

#pragma unroll
    for (int r = 0; r < 3; ++r) {
        const bool first = (r == 0);             // constant after unroll
        float vs[4][8], sacc[4][8];
#pragma unroll
        for (int bb = 0; bb < 4; ++bb) {
            const int b = wave + 8 * bb;
            if (!first) {
                const float* vp = vsum + b * JD + j * 16 + dh * 8;
                const float4 a  = *reinterpret_cast<const float4*>(vp);
                const float4 bq = *reinterpret_cast<const float4*>(vp + 4);
                vs[bb][0]=a.x; vs[bb][1]=a.y; vs[bb][2]=a.z; vs[bb][3]=a.w;
                vs[bb][4]=bq.x; vs[bb][5]=bq.y; vs[bb][6]=bq.z; vs[bb][7]=bq.w;
            }
#pragma unroll
            for (int q = 0; q < 8; ++q) sacc[bb][q] = 0.f;
        }

#pragma unroll
        for (int il = 0; il < ICH; ++il) {
            H8 w8[8];
#pragma unroll
            for (int cc = 0; cc < 8; ++cc)
                w8[cc].i4 = *reinterpret_cast<const int4*>(
                    sWt + il * WIL + cc * WROW + (2 * j + dh) * 16);
#pragma unroll
            for (int bb = 0; bb < 4; ++bb) {
                const int b = wave + 8 * bb;
                H8 xv;
                xv.i4 = *reinterpret_cast<const int4*>(sX + (b * 8 + il) * 16);

                float u[8], tpart = 0.f;
#pragma unroll
                for (int q = 0; q < 8; ++q) {
                    float acc = FDOT2(w8[q].h[0], xv.h[0], 0.f);
                    acc = FDOT2(w8[q].h[1], xv.h[1], acc);
                    acc = FDOT2(w8[q].h[2], xv.h[2], acc);
                    acc = FDOT2(w8[q].h[3], xv.h[3], acc);
                    u[q] = acc;
                    if (!first) tpart = fmaf(acc, vs[bb][q], tpart);
                }
                float c;
                if (first) {
                    c = 0.03125f;                // softmax(0) over 32 j's
                } else {
                    const float t = tpart + __shfl_xor(tpart, 32);
                    const float e = __expf(t);
                    float se = e;
#pragma unroll
                    for (int off = 1; off <= 16; off <<= 1)
                        se += __shfl_xor(se, off);
                    c = e * FAST_RCP(se);
                }
#pragma unroll
                for (int q = 0; q < 8; ++q)
                    sacc[bb][q] = fmaf(c, u[q], sacc[bb][q]);
            }
        }

        // fp16 partial slice, disjoint per block
        __half* pout = partials + (size_t)bid * S_ELEMS;
#pragma unroll
        for (int bb = 0; bb < 4; ++bb) {
            const int b = wave + 8 * bb;
            union { int4 v; __half2 h[4]; } pk;
#pragma unroll
            for (int q = 0; q < 4; ++q)
                pk.h[q] = __floats2half2_rn(sacc[bb][2 * q], sacc[bb][2 * q + 1]);
            *reinterpret_cast<int4*>(pout + b * JD + j * 16 + dh * 8) = pk.v;
        }

        gsync(gbar, 2 * r + 1, bid, tid);

        // ---- reduce: block owns e in [bid*64, bid*64+64) ----
        {
            const int e = bid * 64 + lane;
            float s = 0.f;
            const __half* p = partials + (size_t)wave * 32 * S_ELEMS + e;
#pragma unroll
            for (int n = 0; n < 32; ++n)
                s += __half2float(p[(size_t)n * S_ELEMS]);
            rbuf[wave][lane] = s;
            __syncthreads();
            if (wave == 0) {
                s = 0.f;
#pragma unroll
                for (int k = 0; k < 8; ++k) s += rbuf[k][lane];
                float n2 = s * s;
#pragma unroll
                for (int off = 1; off <= 8; off <<= 1)
                    n2 += __shfl_xor(n2, off);
                const float scale = n2 * FAST_RCP(1.f + n2) * FAST_RSQ(n2 + EPSQ);
                const float v = s * scale;
                if (r == 2) {
                    out[e] = v;
                } else {
                    vacc += v;                   // vsum = sum of v's so far
                    vsum[e] = vacc;
                }
            }
        }
        if (r < 2) gsync(gbar, 2 * r + 2, bid, tid);
    }
}

extern "C" void kernel_launch(void* const* d_in, const int* in_sizes, int n_in,
                              void* d_out, int out_size, void* d_ws, size_t ws_size,
                              hipStream_t stream) {
    const float* x = (const float*)d_in[0];   // [32,2048,8]
    const float* W = (const float*)d_in[1];   // [32,2048,16,8]
    float* out = (float*)d_out;               // [32,32,16]

    // ws: vsum 64KB | partials fp16 8.39MB | gbar 36KB | Wt f16 16.78MB
    float*    vsum     = (float*)d_ws;
    __half*   partials = (__half*)((char*)d_ws + 65536);
    unsigned* gbar     = (unsigned*)((char*)partials + (size_t)NBP * S_ELEMS * 2);
    char*     Wtp      = (char*)gbar + GBAR_WORDS * sizeof(unsigned);

    // zero barrier state (32 flag lines + 256 arrival slots)
    hipMemsetAsync(gbar, 0, GBAR_WORDS * sizeof(unsigned), stream);

    caps_prep<<<ICAP / 4, 256, 0, stream>>>((const float4*)W, Wtp);

    caps_fused<<<NBP, 512, 0, stream>>>((const int4*)Wtp, (const float4*)x,
                                        vsum, partials, out, gbar);
}